// Round 1
// baseline (5659.216 us; speedup 1.0000x reference)
//
#include <hip/hip_runtime.h>

#define NN   100000
#define IND  512
#define HID  128
#define OUTD 64

// ---------------- GEMM1: H1 = relu(F @ W1) ----------------
// F [NN][512], W1 [512][128]. Block tile 64 rows x 128 cols, K-chunk 32.
// 256 threads, each computes 8 rows x 4 cols (cols strided by 32 -> conflict-free LDS reads).
__global__ __launch_bounds__(256) void gemm1_relu_k(const float* __restrict__ F,
                                                    const float* __restrict__ W1,
                                                    float* __restrict__ H1) {
    __shared__ float As[64 * 32];
    __shared__ float Bs[32 * 128];
    const int tid = threadIdx.x;
    const int block_row = blockIdx.x * 64;
    const int ty = tid >> 5;   // 0..7
    const int tx = tid & 31;   // 0..31

    float acc[8][4];
#pragma unroll
    for (int i = 0; i < 8; i++)
#pragma unroll
        for (int j = 0; j < 4; j++) acc[i][j] = 0.f;

    for (int k0 = 0; k0 < IND; k0 += 32) {
        // A tile: 64x32 = 512 float4, 2 per thread
#pragma unroll
        for (int l = 0; l < 2; l++) {
            int f4  = tid + l * 256;
            int row = f4 >> 3;
            int kp  = (f4 & 7) << 2;
            int grow = block_row + row;
            float4 v = make_float4(0.f, 0.f, 0.f, 0.f);
            if (grow < NN) v = *(const float4*)(F + (size_t)grow * IND + k0 + kp);
            *(float4*)(As + row * 32 + kp) = v;
        }
        // B tile: 32x128 = 1024 float4, 4 per thread
#pragma unroll
        for (int l = 0; l < 4; l++) {
            int f4 = tid + l * 256;
            int kk = f4 >> 5;
            int cp = (f4 & 31) << 2;
            *(float4*)(Bs + kk * 128 + cp) = *(const float4*)(W1 + (size_t)(k0 + kk) * HID + cp);
        }
        __syncthreads();
#pragma unroll
        for (int kk = 0; kk < 32; kk++) {
            float a[8], b[4];
#pragma unroll
            for (int i = 0; i < 8; i++) a[i] = As[(i * 8 + ty) * 32 + kk];
#pragma unroll
            for (int j = 0; j < 4; j++) b[j] = Bs[kk * 128 + tx + 32 * j];
#pragma unroll
            for (int i = 0; i < 8; i++)
#pragma unroll
                for (int j = 0; j < 4; j++) acc[i][j] += a[i] * b[j];
        }
        __syncthreads();
    }
#pragma unroll
    for (int i = 0; i < 8; i++) {
        int grow = block_row + i * 8 + ty;
        if (grow < NN) {
#pragma unroll
            for (int j = 0; j < 4; j++) {
                float v = acc[i][j];
                H1[(size_t)grow * HID + tx + 32 * j] = v > 0.f ? v : 0.f;
            }
        }
    }
}

// ---------------- GEMM2: H2 = H1 @ W2 ----------------
// H1 [NN][128], W2 [128][64]. Block tile 64 rows x 64 cols, K-chunk 32.
__global__ __launch_bounds__(256) void gemm2_k(const float* __restrict__ H1,
                                               const float* __restrict__ W2,
                                               float* __restrict__ H2) {
    __shared__ float As[64 * 32];
    __shared__ float Bs[32 * 64];
    const int tid = threadIdx.x;
    const int block_row = blockIdx.x * 64;
    const int ty = tid >> 5;
    const int tx = tid & 31;

    float acc[8][2];
#pragma unroll
    for (int i = 0; i < 8; i++) { acc[i][0] = 0.f; acc[i][1] = 0.f; }

    for (int k0 = 0; k0 < HID; k0 += 32) {
#pragma unroll
        for (int l = 0; l < 2; l++) {
            int f4  = tid + l * 256;
            int row = f4 >> 3;
            int kp  = (f4 & 7) << 2;
            int grow = block_row + row;
            float4 v = make_float4(0.f, 0.f, 0.f, 0.f);
            if (grow < NN) v = *(const float4*)(H1 + (size_t)grow * HID + k0 + kp);
            *(float4*)(As + row * 32 + kp) = v;
        }
        // B tile: 32x64 = 512 float4, 2 per thread
#pragma unroll
        for (int l = 0; l < 2; l++) {
            int f4 = tid + l * 256;
            int kk = f4 >> 4;
            int cp = (f4 & 15) << 2;
            *(float4*)(Bs + kk * 64 + cp) = *(const float4*)(W2 + (size_t)(k0 + kk) * OUTD + cp);
        }
        __syncthreads();
#pragma unroll
        for (int kk = 0; kk < 32; kk++) {
            float a[8];
#pragma unroll
            for (int i = 0; i < 8; i++) a[i] = As[(i * 8 + ty) * 32 + kk];
            float b0 = Bs[kk * 64 + tx];
            float b1 = Bs[kk * 64 + tx + 32];
#pragma unroll
            for (int i = 0; i < 8; i++) { acc[i][0] += a[i] * b0; acc[i][1] += a[i] * b1; }
        }
        __syncthreads();
    }
#pragma unroll
    for (int i = 0; i < 8; i++) {
        int grow = block_row + i * 8 + ty;
        if (grow < NN) {
            H2[(size_t)grow * OUTD + tx]      = acc[i][0];
            H2[(size_t)grow * OUTD + tx + 32] = acc[i][1];
        }
    }
}

// ---------------- Propagate: Z[dst] += w * H[src], 64-dim rows ----------------
// 16 threads per edge, each thread does one float4 gather + 4 atomic adds.
__global__ __launch_bounds__(256) void propagate_k(const float* __restrict__ H,
                                                   const float* __restrict__ ew,
                                                   const int* __restrict__ src,
                                                   const int* __restrict__ dst,
                                                   float* __restrict__ Z,
                                                   int nEdges) {
    long t = (long)blockIdx.x * blockDim.x + threadIdx.x;
    int edge = (int)(t >> 4);
    int lane = (int)(t & 15);
    if (edge >= nEdges) return;
    int s = src[edge];
    int d = dst[edge];
    float w = ew[edge];
    float4 v = *(const float4*)(H + (size_t)s * OUTD + lane * 4);
    float* zd = Z + (size_t)d * OUTD + lane * 4;
    atomicAdd(zd + 0, w * v.x);
    atomicAdd(zd + 1, w * v.y);
    atomicAdd(zd + 2, w * v.z);
    atomicAdd(zd + 3, w * v.w);
}

extern "C" void kernel_launch(void* const* d_in, const int* in_sizes, int n_in,
                              void* d_out, int out_size, void* d_ws, size_t ws_size,
                              hipStream_t stream) {
    const float* F   = (const float*)d_in[0];
    const float* W1  = (const float*)d_in[1];
    const float* W2  = (const float*)d_in[2];
    const float* ew  = (const float*)d_in[3];
    const int*   src = (const int*)d_in[4];
    const int*   dst = (const int*)d_in[5];
    float* out = (float*)d_out;
    const int nE = in_sizes[3];

    // ws layout: h1 [NN*128] | h2 [NN*64]; z1 reuses h1's region (h1 dead after gemm2)
    float* h1 = (float*)d_ws;
    float* h2 = h1 + (size_t)NN * HID;
    float* z1 = h1;  // alias: safe, h1 not read after gemm2

    gemm1_relu_k<<<(NN + 63) / 64, 256, 0, stream>>>(F, W1, h1);
    gemm2_k<<<(NN + 63) / 64, 256, 0, stream>>>(h1, W2, h2);

    hipMemsetAsync(z1, 0, (size_t)NN * OUTD * sizeof(float), stream);
    long total = (long)nE * 16;
    int blocks = (int)((total + 255) / 256);
    propagate_k<<<blocks, 256, 0, stream>>>(h2, ew, src, dst, z1, nE);

    hipMemsetAsync(out, 0, (size_t)NN * OUTD * sizeof(float), stream);
    propagate_k<<<blocks, 256, 0, stream>>>(z1, ew, src, dst, out, nE);
}

// Round 2
// 794.268 us; speedup vs baseline: 7.1251x; 7.1251x over previous
//
#include <hip/hip_runtime.h>

#define NN   100000
#define IND  512
#define HID  128
#define OUTD 64

// ---------------- GEMM1: H1 = relu(F @ W1) ----------------
__global__ __launch_bounds__(256) void gemm1_relu_k(const float* __restrict__ F,
                                                    const float* __restrict__ W1,
                                                    float* __restrict__ H1) {
    __shared__ float As[64 * 32];
    __shared__ float Bs[32 * 128];
    const int tid = threadIdx.x;
    const int block_row = blockIdx.x * 64;
    const int ty = tid >> 5;   // 0..7
    const int tx = tid & 31;   // 0..31

    float acc[8][4];
#pragma unroll
    for (int i = 0; i < 8; i++)
#pragma unroll
        for (int j = 0; j < 4; j++) acc[i][j] = 0.f;

    for (int k0 = 0; k0 < IND; k0 += 32) {
#pragma unroll
        for (int l = 0; l < 2; l++) {
            int f4  = tid + l * 256;
            int row = f4 >> 3;
            int kp  = (f4 & 7) << 2;
            int grow = block_row + row;
            float4 v = make_float4(0.f, 0.f, 0.f, 0.f);
            if (grow < NN) v = *(const float4*)(F + (size_t)grow * IND + k0 + kp);
            *(float4*)(As + row * 32 + kp) = v;
        }
#pragma unroll
        for (int l = 0; l < 4; l++) {
            int f4 = tid + l * 256;
            int kk = f4 >> 5;
            int cp = (f4 & 31) << 2;
            *(float4*)(Bs + kk * 128 + cp) = *(const float4*)(W1 + (size_t)(k0 + kk) * HID + cp);
        }
        __syncthreads();
#pragma unroll
        for (int kk = 0; kk < 32; kk++) {
            float a[8], b[4];
#pragma unroll
            for (int i = 0; i < 8; i++) a[i] = As[(i * 8 + ty) * 32 + kk];
#pragma unroll
            for (int j = 0; j < 4; j++) b[j] = Bs[kk * 128 + tx + 32 * j];
#pragma unroll
            for (int i = 0; i < 8; i++)
#pragma unroll
                for (int j = 0; j < 4; j++) acc[i][j] += a[i] * b[j];
        }
        __syncthreads();
    }
#pragma unroll
    for (int i = 0; i < 8; i++) {
        int grow = block_row + i * 8 + ty;
        if (grow < NN) {
#pragma unroll
            for (int j = 0; j < 4; j++) {
                float v = acc[i][j];
                H1[(size_t)grow * HID + tx + 32 * j] = v > 0.f ? v : 0.f;
            }
        }
    }
}

// ---------------- GEMM2: H2 = H1 @ W2 ----------------
__global__ __launch_bounds__(256) void gemm2_k(const float* __restrict__ H1,
                                               const float* __restrict__ W2,
                                               float* __restrict__ H2) {
    __shared__ float As[64 * 32];
    __shared__ float Bs[32 * 64];
    const int tid = threadIdx.x;
    const int block_row = blockIdx.x * 64;
    const int ty = tid >> 5;
    const int tx = tid & 31;

    float acc[8][2];
#pragma unroll
    for (int i = 0; i < 8; i++) { acc[i][0] = 0.f; acc[i][1] = 0.f; }

    for (int k0 = 0; k0 < HID; k0 += 32) {
#pragma unroll
        for (int l = 0; l < 2; l++) {
            int f4  = tid + l * 256;
            int row = f4 >> 3;
            int kp  = (f4 & 7) << 2;
            int grow = block_row + row;
            float4 v = make_float4(0.f, 0.f, 0.f, 0.f);
            if (grow < NN) v = *(const float4*)(H1 + (size_t)grow * HID + k0 + kp);
            *(float4*)(As + row * 32 + kp) = v;
        }
#pragma unroll
        for (int l = 0; l < 2; l++) {
            int f4 = tid + l * 256;
            int kk = f4 >> 4;
            int cp = (f4 & 15) << 2;
            *(float4*)(Bs + kk * 64 + cp) = *(const float4*)(W2 + (size_t)(k0 + kk) * OUTD + cp);
        }
        __syncthreads();
#pragma unroll
        for (int kk = 0; kk < 32; kk++) {
            float a[8];
#pragma unroll
            for (int i = 0; i < 8; i++) a[i] = As[(i * 8 + ty) * 32 + kk];
            float b0 = Bs[kk * 64 + tx];
            float b1 = Bs[kk * 64 + tx + 32];
#pragma unroll
            for (int i = 0; i < 8; i++) { acc[i][0] += a[i] * b0; acc[i][1] += a[i] * b1; }
        }
        __syncthreads();
    }
#pragma unroll
    for (int i = 0; i < 8; i++) {
        int grow = block_row + i * 8 + ty;
        if (grow < NN) {
            H2[(size_t)grow * OUTD + tx]      = acc[i][0];
            H2[(size_t)grow * OUTD + tx + 32] = acc[i][1];
        }
    }
}

// ---------------- CSR build ----------------
__global__ __launch_bounds__(256) void hist_k(const int* __restrict__ dst,
                                              int* __restrict__ deg, int nE) {
    int e = blockIdx.x * blockDim.x + threadIdx.x;
    if (e < nE) atomicAdd(&deg[dst[e]], 1);
}

// Block-level reduce: blockSums[b] = sum of deg[b*256 .. b*256+255]
__global__ __launch_bounds__(256) void scan_reduce_k(const int* __restrict__ deg,
                                                     int* __restrict__ blockSums) {
    __shared__ int s[256];
    int tid = threadIdx.x;
    int gid = blockIdx.x * 256 + tid;
    s[tid] = (gid < NN) ? deg[gid] : 0;
    __syncthreads();
    for (int off = 128; off > 0; off >>= 1) {
        if (tid < off) s[tid] += s[tid + off];
        __syncthreads();
    }
    if (tid == 0) blockSums[blockIdx.x] = s[0];
}

// Single-block exclusive scan of blockSums (nBlocks <= 512)
__global__ __launch_bounds__(512) void scan_top_k(int* __restrict__ blockSums, int n) {
    __shared__ int s[512];
    int tid = threadIdx.x;
    int v = (tid < n) ? blockSums[tid] : 0;
    s[tid] = v;
    __syncthreads();
    for (int off = 1; off < 512; off <<= 1) {
        int t = (tid >= off) ? s[tid - off] : 0;
        __syncthreads();
        s[tid] += t;
        __syncthreads();
    }
    if (tid < n) blockSums[tid] = s[tid] - v;  // exclusive
}

// Per-block local scan + offset; writes rowStart, cursor, and rowStart[NN]
__global__ __launch_bounds__(256) void scan_finish_k(const int* __restrict__ deg,
                                                     const int* __restrict__ blockSums,
                                                     int* __restrict__ rowStart,
                                                     int* __restrict__ cursor) {
    __shared__ int s[256];
    int tid = threadIdx.x;
    int gid = blockIdx.x * 256 + tid;
    int v = (gid < NN) ? deg[gid] : 0;
    s[tid] = v;
    __syncthreads();
    for (int off = 1; off < 256; off <<= 1) {
        int t = (tid >= off) ? s[tid - off] : 0;
        __syncthreads();
        s[tid] += t;
        __syncthreads();
    }
    int base = blockSums[blockIdx.x];
    int excl = base + s[tid] - v;
    if (gid < NN) { rowStart[gid] = excl; cursor[gid] = excl; }
    if (gid == NN - 1) rowStart[NN] = base + s[tid];  // total edges
}

__global__ __launch_bounds__(256) void scatter_k(const int* __restrict__ src,
                                                 const int* __restrict__ dst,
                                                 const float* __restrict__ ew,
                                                 int* __restrict__ cursor,
                                                 int2* __restrict__ srcW, int nE) {
    int e = blockIdx.x * blockDim.x + threadIdx.x;
    if (e >= nE) return;
    int d = dst[e];
    int pos = atomicAdd(&cursor[d], 1);
    srcW[pos] = make_int2(src[e], __float_as_int(ew[e]));
}

// ---------------- Pull propagate: one wave per dst node, lane = feature ----------------
__global__ __launch_bounds__(256) void propagate_pull_k(const float* __restrict__ H,
                                                        const int2* __restrict__ srcW,
                                                        const int* __restrict__ rowStart,
                                                        float* __restrict__ Z) {
    int wave = (int)((blockIdx.x * (long)blockDim.x + threadIdx.x) >> 6);
    int lane = threadIdx.x & 63;
    if (wave >= NN) return;
    int beg = rowStart[wave];
    int end = rowStart[wave + 1];
    float acc = 0.f;
    int i = beg;
    for (; i + 4 <= end; i += 4) {
        int2 e0 = srcW[i], e1 = srcW[i + 1], e2 = srcW[i + 2], e3 = srcW[i + 3];
        float h0 = H[(size_t)e0.x * OUTD + lane];
        float h1 = H[(size_t)e1.x * OUTD + lane];
        float h2 = H[(size_t)e2.x * OUTD + lane];
        float h3 = H[(size_t)e3.x * OUTD + lane];
        acc += __int_as_float(e0.y) * h0;
        acc += __int_as_float(e1.y) * h1;
        acc += __int_as_float(e2.y) * h2;
        acc += __int_as_float(e3.y) * h3;
    }
    for (; i < end; i++) {
        int2 e = srcW[i];
        acc += __int_as_float(e.y) * H[(size_t)e.x * OUTD + lane];
    }
    Z[(size_t)wave * OUTD + lane] = acc;
}

extern "C" void kernel_launch(void* const* d_in, const int* in_sizes, int n_in,
                              void* d_out, int out_size, void* d_ws, size_t ws_size,
                              hipStream_t stream) {
    const float* F   = (const float*)d_in[0];
    const float* W1  = (const float*)d_in[1];
    const float* W2  = (const float*)d_in[2];
    const float* ew  = (const float*)d_in[3];
    const int*   src = (const int*)d_in[4];
    const int*   dst = (const int*)d_in[5];
    float* out = (float*)d_out;
    const int nE = in_sizes[3];

    // ---- workspace layout (16B-aligned chunks) ----
    char* p = (char*)d_ws;
    float* h1       = (float*)p;             p += (size_t)NN * HID * sizeof(float);   // 51.2 MB
    float* h2       = (float*)p;             p += (size_t)NN * OUTD * sizeof(float);  // 25.6 MB
    int*   deg      = (int*)p;               p += (size_t)NN * sizeof(int);
    int*   rowStart = (int*)p;               p += (size_t)(NN + 16) * sizeof(int);
    int*   cursor   = (int*)p;               p += (size_t)NN * sizeof(int);
    int*   blockSums= (int*)p;               p += 512 * sizeof(int);
    int2*  srcW     = (int2*)p;              p += (size_t)nE * sizeof(int2);          // 25.6 MB
    float* z1       = h1;  // alias: h1 dead after gemm2

    const int nScanBlocks = (NN + 255) / 256;  // 391

    // ---- CSR build (graph is shared by both propagates) ----
    hipMemsetAsync(deg, 0, (size_t)NN * sizeof(int), stream);
    hist_k<<<(nE + 255) / 256, 256, 0, stream>>>(dst, deg, nE);
    scan_reduce_k<<<nScanBlocks, 256, 0, stream>>>(deg, blockSums);
    scan_top_k<<<1, 512, 0, stream>>>(blockSums, nScanBlocks);
    scan_finish_k<<<nScanBlocks, 256, 0, stream>>>(deg, blockSums, rowStart, cursor);
    scatter_k<<<(nE + 255) / 256, 256, 0, stream>>>(src, dst, ew, cursor, srcW, nE);

    // ---- NN layers ----
    gemm1_relu_k<<<(NN + 63) / 64, 256, 0, stream>>>(F, W1, h1);
    gemm2_k<<<(NN + 63) / 64, 256, 0, stream>>>(h1, W2, h2);

    // ---- 2x pull-propagate, no atomics ----
    long waves = NN;
    int blocks = (int)((waves * 64 + 255) / 256);
    propagate_pull_k<<<blocks, 256, 0, stream>>>(h2, srcW, rowStart, z1);
    propagate_pull_k<<<blocks, 256, 0, stream>>>(z1, srcW, rowStart, out);
}

// Round 3
// 614.112 us; speedup vs baseline: 9.2153x; 1.2934x over previous
//
#include <hip/hip_runtime.h>

#define NN   100000
#define IND  512
#define HID  128
#define OUTD 64

typedef _Float16 half8_t __attribute__((ext_vector_type(8)));
typedef _Float16 half4_t __attribute__((ext_vector_type(4)));
typedef float f32x4 __attribute__((ext_vector_type(4)));

// ---------------- prep: W1t[c][k] = (f16)W1[k][c], W2t[c][k] = (f16)W2[k][c] ----------------
__global__ __launch_bounds__(256) void prep_k(const float* __restrict__ W1,
                                              const float* __restrict__ W2,
                                              _Float16* __restrict__ W1t,
                                              _Float16* __restrict__ W2t) {
    int idx = blockIdx.x * 256 + threadIdx.x;
    if (idx < IND * HID) {             // W1t [128][512]
        int c = idx >> 9, k = idx & 511;
        W1t[idx] = (_Float16)W1[k * HID + c];
    }
    if (idx < HID * OUTD) {            // W2t [64][128]
        int c = idx >> 7, k = idx & 127;
        W2t[idx] = (_Float16)W2[k * OUTD + c];
    }
}

// ---------------- fused GEMM: H2 = relu(F @ W1) @ W2, f16 MFMA ----------------
// Block: 128 rows, 4 waves; wave w owns rows w*32..w*32+31.
// Stage 1: h1 strip 32x128 in acc (MFMA over K=512, chunks of 64).
// Stage 2: strip -> wave-private LDS (f16) -> MFMA with W2t -> h2 f32.
__global__ __launch_bounds__(256) void fused_gemm_k(const float* __restrict__ F,
                                                    const _Float16* __restrict__ W1t,
                                                    const _Float16* __restrict__ W2t,
                                                    float* __restrict__ H2) {
    __shared__ _Float16 At[128 * 64];       // F chunk, swizzled
    __shared__ _Float16 Bt[128 * 64];       // W1t chunk (col-major k), swizzled
    __shared__ _Float16 W2s[64 * 128];      // W2t full, swizzled
    __shared__ _Float16 H1s[4][32 * 128];   // per-wave h1 strips, swizzled

    const int tid  = threadIdx.x;
    const int wid  = tid >> 6;
    const int lane = tid & 63;
    const int l15  = lane & 15;
    const int l4   = lane >> 4;
    const int brow = blockIdx.x * 128;

    // stage W2s once: 64 rows x 16 slots(8 halves)
#pragma unroll
    for (int i = 0; i < 4; i++) {
        int idx = i * 256 + tid;
        int r = idx >> 4, s = idx & 15;
        int u = (r * 128 + s * 8) ^ ((r & 7) << 3);
        *(uint4*)(&W2s[u]) = *(const uint4*)(W2t + r * 128 + s * 8);
    }

    f32x4 acc[2][8];
#pragma unroll
    for (int mt = 0; mt < 2; mt++)
#pragma unroll
        for (int nt = 0; nt < 8; nt++) acc[mt][nt] = (f32x4)0.f;

    for (int chunk = 0; chunk < 8; chunk++) {
        const int kc = chunk * 64;
        // F tile: 128 rows x 16 float4 (convert f32->f16)
#pragma unroll
        for (int i = 0; i < 8; i++) {
            int idx = i * 256 + tid;
            int r = idx >> 4, c4 = idx & 15;
            int gr = brow + r; if (gr >= NN) gr = NN - 1;
            float4 v = *(const float4*)(F + (size_t)gr * IND + kc + c4 * 4);
            half4_t h; h.x = (_Float16)v.x; h.y = (_Float16)v.y; h.z = (_Float16)v.z; h.w = (_Float16)v.w;
            int u = (r * 64 + c4 * 4) ^ ((r & 7) << 3);
            *(half4_t*)(&At[u]) = h;
        }
        // W1t tile: 128 rows x 8 slots(8 halves), already f16
#pragma unroll
        for (int i = 0; i < 4; i++) {
            int idx = i * 256 + tid;
            int r = idx >> 3, s = idx & 7;
            int u = (r * 64 + s * 8) ^ ((r & 7) << 3);
            *(uint4*)(&Bt[u]) = *(const uint4*)(W1t + (size_t)r * IND + kc + s * 8);
        }
        __syncthreads();
#pragma unroll
        for (int kk = 0; kk < 2; kk++) {
            const int kc2 = kk * 32;
            half8_t af[2];
#pragma unroll
            for (int mt = 0; mt < 2; mt++) {
                int rloc = wid * 32 + mt * 16 + l15;
                int u = (rloc * 64 + kc2 + l4 * 8) ^ ((rloc & 7) << 3);
                af[mt] = *(half8_t*)(&At[u]);
            }
#pragma unroll
            for (int nt = 0; nt < 8; nt++) {
                int cloc = nt * 16 + l15;
                int u = (cloc * 64 + kc2 + l4 * 8) ^ ((cloc & 7) << 3);
                half8_t bf = *(half8_t*)(&Bt[u]);
                acc[0][nt] = __builtin_amdgcn_mfma_f32_16x16x32_f16(af[0], bf, acc[0][nt], 0, 0, 0);
                acc[1][nt] = __builtin_amdgcn_mfma_f32_16x16x32_f16(af[1], bf, acc[1][nt], 0, 0, 0);
            }
        }
        __syncthreads();
    }

    // relu + f16 + write wave-private strip [32][128]
#pragma unroll
    for (int mt = 0; mt < 2; mt++)
#pragma unroll
        for (int nt = 0; nt < 8; nt++)
#pragma unroll
            for (int r = 0; r < 4; r++) {
                int rloc = mt * 16 + l4 * 4 + r;
                int col  = nt * 16 + l15;
                float v = acc[mt][nt][r];
                v = v > 0.f ? v : 0.f;
                int u = (rloc * 128 + col) ^ ((rloc & 7) << 3);
                H1s[wid][u] = (_Float16)v;
            }
    // wave-private LDS: compiler inserts lgkmcnt waits on dependency; no barrier needed

    f32x4 acc2[2][4];
#pragma unroll
    for (int mt = 0; mt < 2; mt++)
#pragma unroll
        for (int nt = 0; nt < 4; nt++) acc2[mt][nt] = (f32x4)0.f;

#pragma unroll
    for (int kk = 0; kk < 4; kk++) {
        const int kc = kk * 32;
        half8_t a2[2];
#pragma unroll
        for (int mt = 0; mt < 2; mt++) {
            int rloc = mt * 16 + l15;
            int u = (rloc * 128 + kc + l4 * 8) ^ ((rloc & 7) << 3);
            a2[mt] = *(half8_t*)(&H1s[wid][u]);
        }
#pragma unroll
        for (int nt = 0; nt < 4; nt++) {
            int c = nt * 16 + l15;
            int u = (c * 128 + kc + l4 * 8) ^ ((c & 7) << 3);
            half8_t b2 = *(half8_t*)(&W2s[u]);
            acc2[0][nt] = __builtin_amdgcn_mfma_f32_16x16x32_f16(a2[0], b2, acc2[0][nt], 0, 0, 0);
            acc2[1][nt] = __builtin_amdgcn_mfma_f32_16x16x32_f16(a2[1], b2, acc2[1][nt], 0, 0, 0);
        }
    }
#pragma unroll
    for (int mt = 0; mt < 2; mt++)
#pragma unroll
        for (int nt = 0; nt < 4; nt++)
#pragma unroll
            for (int r = 0; r < 4; r++) {
                int grow = brow + wid * 32 + mt * 16 + l4 * 4 + r;
                if (grow < NN) H2[(size_t)grow * OUTD + nt * 16 + l15] = acc2[mt][nt][r];
            }
}

// ---------------- CSR build ----------------
__global__ __launch_bounds__(256) void hist_k(const int* __restrict__ dst,
                                              int* __restrict__ deg, int nE) {
    int e = blockIdx.x * blockDim.x + threadIdx.x;
    if (e < nE) atomicAdd(&deg[dst[e]], 1);
}

__global__ __launch_bounds__(256) void scan_reduce_k(const int* __restrict__ deg,
                                                     int* __restrict__ blockSums) {
    __shared__ int s[256];
    int tid = threadIdx.x;
    int gid = blockIdx.x * 256 + tid;
    s[tid] = (gid < NN) ? deg[gid] : 0;
    __syncthreads();
    for (int off = 128; off > 0; off >>= 1) {
        if (tid < off) s[tid] += s[tid + off];
        __syncthreads();
    }
    if (tid == 0) blockSums[blockIdx.x] = s[0];
}

__global__ __launch_bounds__(512) void scan_top_k(int* __restrict__ blockSums, int n) {
    __shared__ int s[512];
    int tid = threadIdx.x;
    int v = (tid < n) ? blockSums[tid] : 0;
    s[tid] = v;
    __syncthreads();
    for (int off = 1; off < 512; off <<= 1) {
        int t = (tid >= off) ? s[tid - off] : 0;
        __syncthreads();
        s[tid] += t;
        __syncthreads();
    }
    if (tid < n) blockSums[tid] = s[tid] - v;
}

__global__ __launch_bounds__(256) void scan_finish_k(const int* __restrict__ deg,
                                                     const int* __restrict__ blockSums,
                                                     int* __restrict__ rowStart,
                                                     int* __restrict__ cursor) {
    __shared__ int s[256];
    int tid = threadIdx.x;
    int gid = blockIdx.x * 256 + tid;
    int v = (gid < NN) ? deg[gid] : 0;
    s[tid] = v;
    __syncthreads();
    for (int off = 1; off < 256; off <<= 1) {
        int t = (tid >= off) ? s[tid - off] : 0;
        __syncthreads();
        s[tid] += t;
        __syncthreads();
    }
    int base = blockSums[blockIdx.x];
    int excl = base + s[tid] - v;
    if (gid < NN) { rowStart[gid] = excl; cursor[gid] = excl; }
    if (gid == NN - 1) rowStart[NN] = base + s[tid];
}

// dst-range-filtered scatter: pass confines writes to a small, cache-resident window.
// payload packs src (17b) | weight q15 (15b) into 4B.
__global__ __launch_bounds__(256) void scatter_k(const int* __restrict__ src,
                                                 const int* __restrict__ dst,
                                                 const float* __restrict__ ew,
                                                 int* __restrict__ cursor,
                                                 unsigned* __restrict__ srcW,
                                                 int nE, int lo, int hi) {
    int e = blockIdx.x * blockDim.x + threadIdx.x;
    if (e >= nE) return;
    int d = dst[e];
    if (d < lo || d >= hi) return;
    int pos = atomicAdd(&cursor[d], 1);
    int q = (int)(ew[e] * 32768.f + 0.5f);
    if (q > 32767) q = 32767;
    srcW[pos] = ((unsigned)src[e] << 15) | (unsigned)q;
}

// ---------------- Pull propagate: one wave per dst node, lane = feature ----------------
__global__ __launch_bounds__(256) void propagate_pull_k(const float* __restrict__ H,
                                                        const unsigned* __restrict__ srcW,
                                                        const int* __restrict__ rowStart,
                                                        float* __restrict__ Z) {
    int wave = (int)((blockIdx.x * (long)blockDim.x + threadIdx.x) >> 6);
    int lane = threadIdx.x & 63;
    if (wave >= NN) return;
    int beg = rowStart[wave];
    int end = rowStart[wave + 1];
    float acc = 0.f;
    int i = beg;
    for (; i + 4 <= end; i += 4) {
        unsigned u0 = srcW[i], u1 = srcW[i + 1], u2 = srcW[i + 2], u3 = srcW[i + 3];
        float h0 = H[(size_t)(u0 >> 15) * OUTD + lane];
        float h1 = H[(size_t)(u1 >> 15) * OUTD + lane];
        float h2 = H[(size_t)(u2 >> 15) * OUTD + lane];
        float h3 = H[(size_t)(u3 >> 15) * OUTD + lane];
        acc += (float)(int)(u0 & 32767u) * h0;
        acc += (float)(int)(u1 & 32767u) * h1;
        acc += (float)(int)(u2 & 32767u) * h2;
        acc += (float)(int)(u3 & 32767u) * h3;
    }
    for (; i < end; i++) {
        unsigned u = srcW[i];
        acc += (float)(int)(u & 32767u) * H[(size_t)(u >> 15) * OUTD + lane];
    }
    Z[(size_t)wave * OUTD + lane] = acc * (1.f / 32768.f);
}

extern "C" void kernel_launch(void* const* d_in, const int* in_sizes, int n_in,
                              void* d_out, int out_size, void* d_ws, size_t ws_size,
                              hipStream_t stream) {
    const float* F   = (const float*)d_in[0];
    const float* W1  = (const float*)d_in[1];
    const float* W2  = (const float*)d_in[2];
    const float* ew  = (const float*)d_in[3];
    const int*   src = (const int*)d_in[4];
    const int*   dst = (const int*)d_in[5];
    float* out = (float*)d_out;
    const int nE = in_sizes[3];

    // ---- workspace layout ----
    char* p = (char*)d_ws;
    float*     h2       = (float*)p;     p += (size_t)NN * OUTD * sizeof(float);   // 25.6 MB
    float*     z1       = (float*)p;     p += (size_t)NN * OUTD * sizeof(float);   // 25.6 MB
    _Float16*  W1t      = (_Float16*)p;  p += (size_t)HID * IND * sizeof(_Float16);
    _Float16*  W2t      = (_Float16*)p;  p += (size_t)OUTD * HID * sizeof(_Float16);
    int*       deg      = (int*)p;       p += (size_t)NN * sizeof(int);
    int*       rowStart = (int*)p;       p += (size_t)(NN + 16) * sizeof(int);
    int*       cursor   = (int*)p;       p += (size_t)NN * sizeof(int);
    int*       blockSums= (int*)p;       p += 512 * sizeof(int);
    unsigned*  srcW     = (unsigned*)p;  p += (size_t)nE * sizeof(unsigned);       // 12.8 MB

    const int nScanBlocks = (NN + 255) / 256;   // 391
    const int nEdgeBlocks = (nE + 255) / 256;

    // ---- weight prep + CSR build ----
    prep_k<<<(IND * HID + 255) / 256, 256, 0, stream>>>(W1, W2, W1t, W2t);
    hipMemsetAsync(deg, 0, (size_t)NN * sizeof(int), stream);
    hist_k<<<nEdgeBlocks, 256, 0, stream>>>(dst, deg, nE);
    scan_reduce_k<<<nScanBlocks, 256, 0, stream>>>(deg, blockSums);
    scan_top_k<<<1, 512, 0, stream>>>(blockSums, nScanBlocks);
    scan_finish_k<<<nScanBlocks, 256, 0, stream>>>(deg, blockSums, rowStart, cursor);

    // 8 dst-range passes: each pass's srcW window ~1.6 MB -> cache-resident line assembly
    const int NPASS = 8;
    const int span = (NN + NPASS - 1) / NPASS;
    for (int pss = 0; pss < NPASS; pss++) {
        int lo = pss * span, hi = lo + span;
        scatter_k<<<nEdgeBlocks, 256, 0, stream>>>(src, dst, ew, cursor, srcW, nE, lo, hi);
    }

    // ---- fused NN layers (f16 MFMA) ----
    fused_gemm_k<<<(NN + 127) / 128, 256, 0, stream>>>(F, W1t, W2t, h2);

    // ---- 2x pull-propagate ----
    int blocks = (int)(((long)NN * 64 + 255) / 256);
    propagate_pull_k<<<blocks, 256, 0, stream>>>(h2, srcW, rowStart, z1);
    propagate_pull_k<<<blocks, 256, 0, stream>>>(z1, srcW, rowStart, out);
}